// Round 1
// baseline (427.714 us; speedup 1.0000x reference)
//
#include <hip/hip_runtime.h>

#define F1 33

// cos(2*pi*m/64); sin(2*pi*m/64) = TWD[(m+48)&63]
constexpr float TWD[64] = {
   1.00000000f,  0.99518473f,  0.98078528f,  0.95694034f,
   0.92387953f,  0.88192126f,  0.83146961f,  0.77301045f,
   0.70710678f,  0.63439328f,  0.55557023f,  0.47139674f,
   0.38268343f,  0.29028468f,  0.19509032f,  0.09801714f,
   0.00000000f, -0.09801714f, -0.19509032f, -0.29028468f,
  -0.38268343f, -0.47139674f, -0.55557023f, -0.63439328f,
  -0.70710678f, -0.77301045f, -0.83146961f, -0.88192126f,
  -0.92387953f, -0.95694034f, -0.98078528f, -0.99518473f,
  -1.00000000f, -0.99518473f, -0.98078528f, -0.95694034f,
  -0.92387953f, -0.88192126f, -0.83146961f, -0.77301045f,
  -0.70710678f, -0.63439328f, -0.55557023f, -0.47139674f,
  -0.38268343f, -0.29028468f, -0.19509032f, -0.09801714f,
   0.00000000f,  0.09801714f,  0.19509032f,  0.29028468f,
   0.38268343f,  0.47139674f,  0.55557023f,  0.63439328f,
   0.70710678f,  0.77301045f,  0.83146961f,  0.88192126f,
   0.92387953f,  0.95694034f,  0.98078528f,  0.99518473f,
};

// ---------------- K0: deterministic sort of modes by k (tie: original l) ----
__global__ __launch_bounds__(256) void k_sort(const int* __restrict__ mask,
                                              int* __restrict__ sorted) {
  __shared__ int ks[256];
  int t = threadIdx.x;
  int mi = mask[t];
  int j = mi / F1;
  int k = mi - j * F1;
  ks[t] = k;
  __syncthreads();
  int mykey = (k << 8) | t;
  int rank = 0;
  for (int l2 = 0; l2 < 256; ++l2)
    rank += (((ks[l2] << 8) | l2) < mykey);
  sorted[rank] = (k << 16) | (j << 8) | t;
}

// ---------------- K1: forward. thread = one (b,h,i,s0) row. ----------------
// stage A: 33-bin DFT along s1 with compile-time twiddles (all in registers)
// stage B: gather 256 modes: 32-point DFT along s0 via LDS, 4 units/block
__global__ __launch_bounds__(128) void k_fwd(const float* __restrict__ x,
                                             const int* __restrict__ mask,
                                             float2* __restrict__ xm) {
  __shared__ float2 rbuf[128][35];   // [row][k] (pad 35 vs bank conflicts)
  __shared__ float2 cs32[32];        // (cos,sin)(2*pi*m/32)
  int t = threadIdx.x;
  if (t < 32) cs32[t] = make_float2(TWD[(2 * t) & 63], TWD[(2 * t + 48) & 63]);

  size_t row = (size_t)blockIdx.x * 128 + t;
  const float4* xp = (const float4*)(x + row * 64);
  float xr[64];
#pragma unroll
  for (int q = 0; q < 16; ++q) {
    float4 v = xp[q];
    xr[4 * q + 0] = v.x; xr[4 * q + 1] = v.y;
    xr[4 * q + 2] = v.z; xr[4 * q + 3] = v.w;
  }
  float aR[33], aI[33];
#pragma unroll
  for (int k = 0; k < 33; ++k) { aR[k] = 0.f; aI[k] = 0.f; }
#pragma unroll
  for (int s1 = 0; s1 < 64; ++s1) {
    float xv = xr[s1];
#pragma unroll
    for (int k = 0; k < 33; ++k) {
      constexpr int dummy = 0; (void)dummy;
      int m = (k * s1) & 63;                 // compile-time under full unroll
      aR[k] = fmaf(xv,  TWD[m], aR[k]);
      aI[k] = fmaf(xv, -TWD[(m + 48) & 63], aI[k]);   // -sin
    }
  }
#pragma unroll
  for (int k = 0; k < 33; ++k) rbuf[t][k] = make_float2(aR[k], aI[k]);

  // mode info (2 modes per thread)
  int jl[2], kl[2];
#pragma unroll
  for (int p = 0; p < 2; ++p) {
    int mi = mask[t + 128 * p];
    jl[p] = mi / F1;
    kl[p] = mi - jl[p] * F1;
  }
  __syncthreads();

  float2 acc[2][4];
#pragma unroll
  for (int p = 0; p < 2; ++p)
#pragma unroll
    for (int u = 0; u < 4; ++u) acc[p][u] = make_float2(0.f, 0.f);

  for (int s0 = 0; s0 < 32; ++s0) {
#pragma unroll
    for (int p = 0; p < 2; ++p) {
      float2 cs = cs32[(jl[p] * s0) & 31];   // (cos, sin)
#pragma unroll
      for (int u = 0; u < 4; ++u) {
        float2 rv = rbuf[u * 32 + s0][kl[p]];
        // (rr + i ri) * (c - i s)
        acc[p][u].x = fmaf(rv.x, cs.x, fmaf(rv.y,  cs.y, acc[p][u].x));
        acc[p][u].y = fmaf(rv.y, cs.x, fmaf(-rv.x, cs.y, acc[p][u].y));
      }
    }
  }
  size_t ub = (size_t)blockIdx.x * 4;
#pragma unroll
  for (int p = 0; p < 2; ++p)
#pragma unroll
    for (int u = 0; u < 4; ++u)
      xm[(ub + u) * 256 + t + 128 * p] = acc[p][u];
}

// ---------------- K2: om[b,h,o,l] = sum_i xm[b,h,i,l] * W[h,i,o,l] ----------
// block = (h, l-group of 8). 512 threads = (bh2, lp4, o64).
__global__ __launch_bounds__(512) void k_mix(const float2* __restrict__ xm,
                                             const float* __restrict__ wr,
                                             const float* __restrict__ wi,
                                             float2* __restrict__ om) {
  __shared__ float2 Asm[8][33][9];   // [i][b][l] (b-dim 33, l-dim 9 pads)
  __shared__ float2 Wsm[8][8][64];   // [i][l][o]
  int t = threadIdx.x;
  int h  = blockIdx.x >> 5;
  int lb = (blockIdx.x & 31) * 8;

  int o  = t & 63;
  int lp = (t >> 6) & 3;
  int bh = t >> 8;                   // 0/1 -> b range 16

  float2 acc[16][2];
#pragma unroll
  for (int bb = 0; bb < 16; ++bb) {
    acc[bb][0] = make_float2(0.f, 0.f);
    acc[bb][1] = make_float2(0.f, 0.f);
  }

  for (int ic = 0; ic < 8; ++ic) {
    __syncthreads();
    // stage A tile: chunks c = t, t+512 over 1024 (b,i,lp) float4 chunks
#pragma unroll
    for (int q = 0; q < 2; ++q) {
      int c = t + 512 * q;
      int lp4 = c & 3, ii = (c >> 2) & 7, b = c >> 5;
      const float4* src = (const float4*)(xm + (size_t)(((b * 8 + h) * 64) + ic * 8 + ii) * 256 + lb + lp4 * 2);
      float4 v = *src;
      Asm[ii][b][lp4 * 2 + 0] = make_float2(v.x, v.y);
      Asm[ii][b][lp4 * 2 + 1] = make_float2(v.z, v.w);
    }
    // stage W tile: chunks c over 1024 (i,o,lh) float4 chunks (re+im planes)
#pragma unroll
    for (int q = 0; q < 2; ++q) {
      int c = t + 512 * q;
      int lh = c & 1, oo = (c >> 1) & 63, ii = c >> 7;
      size_t gidx = (size_t)((h * 64 + ic * 8 + ii) * 64 + oo) * 256 + lb + lh * 4;
      float4 vr = *(const float4*)(wr + gidx);
      float4 vi = *(const float4*)(wi + gidx);
      Wsm[ii][lh * 4 + 0][oo] = make_float2(vr.x, vi.x);
      Wsm[ii][lh * 4 + 1][oo] = make_float2(vr.y, vi.y);
      Wsm[ii][lh * 4 + 2][oo] = make_float2(vr.z, vi.z);
      Wsm[ii][lh * 4 + 3][oo] = make_float2(vr.w, vi.w);
    }
    __syncthreads();
#pragma unroll
    for (int i = 0; i < 8; ++i) {
      float2 w0 = Wsm[i][lp * 2 + 0][o];
      float2 w1 = Wsm[i][lp * 2 + 1][o];
#pragma unroll
      for (int bb = 0; bb < 16; ++bb) {
        int b = bh * 16 + bb;
        float2 a0 = Asm[i][b][lp * 2 + 0];
        float2 a1 = Asm[i][b][lp * 2 + 1];
        acc[bb][0].x = fmaf(a0.x, w0.x, fmaf(-a0.y, w0.y, acc[bb][0].x));
        acc[bb][0].y = fmaf(a0.x, w0.y, fmaf( a0.y, w0.x, acc[bb][0].y));
        acc[bb][1].x = fmaf(a1.x, w1.x, fmaf(-a1.y, w1.y, acc[bb][1].x));
        acc[bb][1].y = fmaf(a1.x, w1.y, fmaf( a1.y, w1.x, acc[bb][1].y));
      }
    }
  }
#pragma unroll
  for (int bb = 0; bb < 16; ++bb) {
    int b = bh * 16 + bb;
    float4 v = make_float4(acc[bb][0].x, acc[bb][0].y, acc[bb][1].x, acc[bb][1].y);
    *(float4*)(om + (size_t)(((b * 8 + h) * 64) + o) * 256 + lb + lp * 2) = v;
  }
}

// ---------------- K3: inverse. block = 8 (b,h,o) units. ---------------------
// stage 1: T[a,k] = Re( sum_modes om * e^{+2pi i j a/32} ), k-sorted modes,
//          register run-accumulation, LDS atomic flush at k-run boundaries.
// stage 2: y[a,s1] = sum_k T[a,k] * wk*cos(2pi k s1/64)/2048
__global__ __launch_bounds__(256) void k_inv(const float2* __restrict__ om,
                                             const int* __restrict__ sorted,
                                             float* __restrict__ y) {
  __shared__ float2 om8[8][257];
  __shared__ float  T8[8][32][34];
  __shared__ float  c2s[33 * 64];
  __shared__ float2 cs32[32];
  int t = threadIdx.x;
  size_t ub = (size_t)blockIdx.x * 8;

#pragma unroll
  for (int q = 0; q < 8; ++q) {
    int c = t + 256 * q;
    int u = c >> 8, l = c & 255;
    om8[u][l] = om[(ub + u) * 256 + l];
  }
#pragma unroll
  for (int q = 0; q < 9; ++q) {
    int idx = t + 256 * q;
    if (idx < 2112) {
      int k = idx >> 6, s1 = idx & 63;
      float w = (k == 0 || k == 32) ? 1.0f : 2.0f;
      c2s[idx] = w * (1.0f / 2048.0f) * TWD[(k * s1) & 63];
    }
  }
  if (t < 32) cs32[t] = make_float2(TWD[(2 * t) & 63], TWD[(2 * t + 48) & 63]);
  {
    float* tp = &T8[0][0][0];
#pragma unroll
    for (int q = 0; q < 34; ++q) tp[t + 256 * q] = 0.f;
  }
  __syncthreads();

  // ---- stage 1 ----
  {
    int wv = t >> 6;          // wave -> sorted-chunk of 64 modes
    int a  = t & 31;
    int ug = (t >> 5) & 1;    // half-wave -> unit group of 4
    float g[4] = {0.f, 0.f, 0.f, 0.f};
    int kprev = -1;
    for (int it = 0; it < 64; ++it) {
      int e = sorted[wv * 64 + it];
      int k = e >> 16, j = (e >> 8) & 255, l = e & 255;
      if (k != kprev) {                      // wave-uniform branch
        if (kprev >= 0) {
#pragma unroll
          for (int ui = 0; ui < 4; ++ui) {
            atomicAdd(&T8[ug * 4 + ui][a][kprev], g[ui]);
            g[ui] = 0.f;
          }
        }
        kprev = k;
      }
      float2 cs = cs32[(j * a) & 31];
#pragma unroll
      for (int ui = 0; ui < 4; ++ui) {
        float2 ov = om8[ug * 4 + ui][l];
        g[ui] = fmaf(ov.x, cs.x, g[ui]);
        g[ui] = fmaf(-ov.y, cs.y, g[ui]);
      }
    }
#pragma unroll
    for (int ui = 0; ui < 4; ++ui)
      atomicAdd(&T8[ug * 4 + ui][a][kprev], g[ui]);
  }
  __syncthreads();

  // ---- stage 2 ----
  int a  = t >> 3;
  int so = t & 7;
  float acc[8][8];
#pragma unroll
  for (int u = 0; u < 8; ++u)
#pragma unroll
    for (int s = 0; s < 8; ++s) acc[u][s] = 0.f;

  for (int k = 0; k < 33; ++k) {
    float4 cA = *(const float4*)&c2s[k * 64 + so * 8];
    float4 cB = *(const float4*)&c2s[k * 64 + so * 8 + 4];
#pragma unroll
    for (int u = 0; u < 8; ++u) {
      float tv = T8[u][a][k];
      acc[u][0] = fmaf(tv, cA.x, acc[u][0]);
      acc[u][1] = fmaf(tv, cA.y, acc[u][1]);
      acc[u][2] = fmaf(tv, cA.z, acc[u][2]);
      acc[u][3] = fmaf(tv, cA.w, acc[u][3]);
      acc[u][4] = fmaf(tv, cB.x, acc[u][4]);
      acc[u][5] = fmaf(tv, cB.y, acc[u][5]);
      acc[u][6] = fmaf(tv, cB.z, acc[u][6]);
      acc[u][7] = fmaf(tv, cB.w, acc[u][7]);
    }
  }
#pragma unroll
  for (int u = 0; u < 8; ++u) {
    float* yp = y + (ub + u) * 2048 + a * 64 + so * 8;
    *(float4*)(yp + 0) = make_float4(acc[u][0], acc[u][1], acc[u][2], acc[u][3]);
    *(float4*)(yp + 4) = make_float4(acc[u][4], acc[u][5], acc[u][6], acc[u][7]);
  }
}

extern "C" void kernel_launch(void* const* d_in, const int* in_sizes, int n_in,
                              void* d_out, int out_size, void* d_ws, size_t ws_size,
                              hipStream_t stream) {
  const float* x    = (const float*)d_in[0];
  const float* wre  = (const float*)d_in[1];
  const float* wim  = (const float*)d_in[2];
  const int*   mask = (const int*)d_in[3];

  float*  y  = (float*)d_out;
  float2* xm = (float2*)d_out;                        // scratch: dead before y written
  float2* omp = (float2*)d_ws;                        // 33.55 MB
  int* sorted = (int*)((char*)d_ws + 33554432);       // +1 KB

  k_sort<<<1, 256, 0, stream>>>(mask, sorted);
  k_fwd <<<4096, 128, 0, stream>>>(x, mask, xm);
  k_mix <<<256, 512, 0, stream>>>(xm, wre, wim, omp);
  k_inv <<<2048, 256, 0, stream>>>(omp, sorted, y);
}

// Round 2
// 319.875 us; speedup vs baseline: 1.3371x; 1.3371x over previous
//
#include <hip/hip_runtime.h>

#define F1 33

// cos(2*pi*m/64); sin(2*pi*m/64) = TWD[(m+48)&63]
constexpr float TWD[64] = {
   1.00000000f,  0.99518473f,  0.98078528f,  0.95694034f,
   0.92387953f,  0.88192126f,  0.83146961f,  0.77301045f,
   0.70710678f,  0.63439328f,  0.55557023f,  0.47139674f,
   0.38268343f,  0.29028468f,  0.19509032f,  0.09801714f,
   0.00000000f, -0.09801714f, -0.19509032f, -0.29028468f,
  -0.38268343f, -0.47139674f, -0.55557023f, -0.63439328f,
  -0.70710678f, -0.77301045f, -0.83146961f, -0.88192126f,
  -0.92387953f, -0.95694034f, -0.98078528f, -0.99518473f,
  -1.00000000f, -0.99518473f, -0.98078528f, -0.95694034f,
  -0.92387953f, -0.88192126f, -0.83146961f, -0.77301045f,
  -0.70710678f, -0.63439328f, -0.55557023f, -0.47139674f,
  -0.38268343f, -0.29028468f, -0.19509032f, -0.09801714f,
   0.00000000f,  0.09801714f,  0.19509032f,  0.29028468f,
   0.38268343f,  0.47139674f,  0.55557023f,  0.63439328f,
   0.70710678f,  0.77301045f,  0.83146961f,  0.88192126f,
   0.92387953f,  0.95694034f,  0.98078528f,  0.99518473f,
};

// ---------------- K0: deterministic sort of modes by k (tie: original l) ----
__global__ __launch_bounds__(256) void k_sort(const int* __restrict__ mask,
                                              int* __restrict__ sorted) {
  __shared__ int ks[256];
  int t = threadIdx.x;
  int mi = mask[t];
  int j = mi / F1;
  int k = mi - j * F1;
  ks[t] = k;
  __syncthreads();
  int mykey = (k << 8) | t;
  int rank = 0;
  for (int l2 = 0; l2 < 256; ++l2)
    rank += (((ks[l2] << 8) | l2) < mykey);
  sorted[rank] = (k << 16) | (j << 8) | t;
}

// ---------------- K1 v2: forward ------------------------------------------
// 256 threads, 128 rows (4 units). Two threads per row (radix-2 DIT):
//  even lane: 17-bin DFT of even samples (E); odd lane: odd samples (O);
//  shfl_xor(1) exchange, butterfly combine X[k] = E[k] + w64^k O[k]
//  (k>16 via Hermitian conj). Stage B: one k-sorted mode per thread,
//  4 units; sorted order makes rbuf reads wave-broadcasts.
__global__ __launch_bounds__(256, 4) void k_fwd(const float* __restrict__ x,
                                                const int* __restrict__ sorted,
                                                float2* __restrict__ xm) {
  __shared__ float2 rbuf[128][35];   // [row][k], pad 35
  __shared__ float2 cs32[32];        // (cos,sin)(2*pi*m/32)
  int t = threadIdx.x;
  if (t < 32) cs32[t] = make_float2(TWD[(2 * t) & 63], TWD[(2 * t + 48) & 63]);

  int rl  = t >> 1;
  int par = t & 1;
  size_t row = (size_t)blockIdx.x * 128 + rl;
  const float4* xp = (const float4*)(x + row * 64);

  // my subsequence: even lane -> x[2m], odd lane -> x[2m+1]
  float f[32];
#pragma unroll
  for (int q = 0; q < 16; ++q) {
    float4 v = xp[q];                       // lane pairs: same addr (merged)
    f[2 * q + 0] = par ? v.y : v.x;
    f[2 * q + 1] = par ? v.w : v.z;
  }

  // 32-point DFT, bins 0..16 (rest via Hermitian symmetry)
  float mR[17], mI[17];
#pragma unroll
  for (int j = 0; j < 17; ++j) { mR[j] = 0.f; mI[j] = 0.f; }
#pragma unroll
  for (int m = 0; m < 32; ++m) {
    float xv = f[m];
#pragma unroll
    for (int j = 0; j < 17; ++j) {
      const int a = (2 * j * m) & 63;        // compile-time
      const float c = TWD[a];
      const float s = TWD[(a + 48) & 63];
      if (c != 0.0f) mR[j] = fmaf(xv,  c, mR[j]);
      if (s != 0.0f) mI[j] = fmaf(xv, -s, mI[j]);
    }
  }

  // exchange with partner lane (even<->odd)
  float oR[17], oI[17];
#pragma unroll
  for (int j = 0; j < 17; ++j) {
    oR[j] = __shfl_xor(mR[j], 1, 64);
    oI[j] = __shfl_xor(mI[j], 1, 64);
  }

  if (par == 0) {
    // mine = E, other = O;   X[k] = E[k] + w^k O[k],  k = 0..16
#pragma unroll
    for (int k = 0; k <= 16; ++k) {
      const float wr = TWD[k];
      const float s  = TWD[(k + 48) & 63];
      float XR = mR[k];
      float XI = mI[k];
      if (s  != 0.0f) { XR = fmaf( s, oI[k], XR); XI = fmaf(-s, oR[k], XI); }
      if (wr != 0.0f) { XR = fmaf(wr, oR[k], XR); XI = fmaf(wr, oI[k], XI); }
      rbuf[rl][k] = make_float2(XR, XI);
    }
  } else {
    // mine = O, other = E;   k = 17..31: X[k] = conj(E[p]) + w^k conj(O[p]),
    // p = 32-k;              k = 32:     X = E[0] - O[0]  (real)
#pragma unroll
    for (int k = 17; k <= 31; ++k) {
      const float wr = TWD[k];
      const float s  = TWD[(k + 48) & 63];
      const int p = 32 - k;
      float XR = oR[p];
      float XI = -oI[p];
      if (s  != 0.0f) { XR = fmaf(-s, mI[p], XR); XI = fmaf(-s, mR[p], XI); }
      if (wr != 0.0f) { XR = fmaf(wr, mR[p], XR); XI = fmaf(-wr, mI[p], XI); }
      rbuf[rl][k] = make_float2(XR, XI);
    }
    rbuf[rl][32] = make_float2(oR[0] - mR[0], 0.0f);
  }
  __syncthreads();

  // ---- stage B: thread t owns sorted mode t, accumulates 4 units ----
  int e = sorted[t];
  int k = e >> 16, j = (e >> 8) & 255, l = e & 255;
  float2 acc[4];
#pragma unroll
  for (int u = 0; u < 4; ++u) acc[u] = make_float2(0.f, 0.f);

#pragma unroll 4
  for (int s0 = 0; s0 < 32; ++s0) {
    float2 cs = cs32[(j * s0) & 31];         // (cos, sin)
#pragma unroll
    for (int u = 0; u < 4; ++u) {
      float2 rv = rbuf[u * 32 + s0][k];      // wave: ~8 distinct k -> broadcast
      // acc += rv * (c - i s)
      acc[u].x = fmaf(rv.x, cs.x, fmaf(rv.y,  cs.y, acc[u].x));
      acc[u].y = fmaf(rv.y, cs.x, fmaf(-rv.x, cs.y, acc[u].y));
    }
  }
  size_t ub = (size_t)blockIdx.x * 4;
#pragma unroll
  for (int u = 0; u < 4; ++u)
    xm[(ub + u) * 256 + l] = acc[u];
}

// ---------------- K2: om[b,h,o,l] = sum_i xm[b,h,i,l] * W[h,i,o,l] ----------
// block = (h, l-group of 8). 512 threads = (bh2, lp4, o64).
__global__ __launch_bounds__(512) void k_mix(const float2* __restrict__ xm,
                                             const float* __restrict__ wr,
                                             const float* __restrict__ wi,
                                             float2* __restrict__ om) {
  __shared__ float2 Asm[8][33][9];   // [i][b][l] (b-dim 33, l-dim 9 pads)
  __shared__ float2 Wsm[8][8][64];   // [i][l][o]
  int t = threadIdx.x;
  int h  = blockIdx.x >> 5;
  int lb = (blockIdx.x & 31) * 8;

  int o  = t & 63;
  int lp = (t >> 6) & 3;
  int bh = t >> 8;                   // 0/1 -> b range 16

  float2 acc[16][2];
#pragma unroll
  for (int bb = 0; bb < 16; ++bb) {
    acc[bb][0] = make_float2(0.f, 0.f);
    acc[bb][1] = make_float2(0.f, 0.f);
  }

  for (int ic = 0; ic < 8; ++ic) {
    __syncthreads();
    // stage A tile: chunks c = t, t+512 over 1024 (b,i,lp) float4 chunks
#pragma unroll
    for (int q = 0; q < 2; ++q) {
      int c = t + 512 * q;
      int lp4 = c & 3, ii = (c >> 2) & 7, b = c >> 5;
      const float4* src = (const float4*)(xm + (size_t)(((b * 8 + h) * 64) + ic * 8 + ii) * 256 + lb + lp4 * 2);
      float4 v = *src;
      Asm[ii][b][lp4 * 2 + 0] = make_float2(v.x, v.y);
      Asm[ii][b][lp4 * 2 + 1] = make_float2(v.z, v.w);
    }
    // stage W tile: chunks c over 1024 (i,o,lh) float4 chunks (re+im planes)
#pragma unroll
    for (int q = 0; q < 2; ++q) {
      int c = t + 512 * q;
      int lh = c & 1, oo = (c >> 1) & 63, ii = c >> 7;
      size_t gidx = (size_t)((h * 64 + ic * 8 + ii) * 64 + oo) * 256 + lb + lh * 4;
      float4 vr = *(const float4*)(wr + gidx);
      float4 vi = *(const float4*)(wi + gidx);
      Wsm[ii][lh * 4 + 0][oo] = make_float2(vr.x, vi.x);
      Wsm[ii][lh * 4 + 1][oo] = make_float2(vr.y, vi.y);
      Wsm[ii][lh * 4 + 2][oo] = make_float2(vr.z, vi.z);
      Wsm[ii][lh * 4 + 3][oo] = make_float2(vr.w, vi.w);
    }
    __syncthreads();
#pragma unroll
    for (int i = 0; i < 8; ++i) {
      float2 w0 = Wsm[i][lp * 2 + 0][o];
      float2 w1 = Wsm[i][lp * 2 + 1][o];
#pragma unroll
      for (int bb = 0; bb < 16; ++bb) {
        int b = bh * 16 + bb;
        float2 a0 = Asm[i][b][lp * 2 + 0];
        float2 a1 = Asm[i][b][lp * 2 + 1];
        acc[bb][0].x = fmaf(a0.x, w0.x, fmaf(-a0.y, w0.y, acc[bb][0].x));
        acc[bb][0].y = fmaf(a0.x, w0.y, fmaf( a0.y, w0.x, acc[bb][0].y));
        acc[bb][1].x = fmaf(a1.x, w1.x, fmaf(-a1.y, w1.y, acc[bb][1].x));
        acc[bb][1].y = fmaf(a1.x, w1.y, fmaf( a1.y, w1.x, acc[bb][1].y));
      }
    }
  }
#pragma unroll
  for (int bb = 0; bb < 16; ++bb) {
    int b = bh * 16 + bb;
    float4 v = make_float4(acc[bb][0].x, acc[bb][0].y, acc[bb][1].x, acc[bb][1].y);
    *(float4*)(om + (size_t)(((b * 8 + h) * 64) + o) * 256 + lb + lp * 2) = v;
  }
}

// ---------------- K3: inverse. block = 8 (b,h,o) units. ---------------------
__global__ __launch_bounds__(256) void k_inv(const float2* __restrict__ om,
                                             const int* __restrict__ sorted,
                                             float* __restrict__ y) {
  __shared__ float2 om8[8][257];
  __shared__ float  T8[8][32][34];
  __shared__ float  c2s[33 * 64];
  __shared__ float2 cs32[32];
  int t = threadIdx.x;
  size_t ub = (size_t)blockIdx.x * 8;

#pragma unroll
  for (int q = 0; q < 8; ++q) {
    int c = t + 256 * q;
    int u = c >> 8, l = c & 255;
    om8[u][l] = om[(ub + u) * 256 + l];
  }
#pragma unroll
  for (int q = 0; q < 9; ++q) {
    int idx = t + 256 * q;
    if (idx < 2112) {
      int k = idx >> 6, s1 = idx & 63;
      float w = (k == 0 || k == 32) ? 1.0f : 2.0f;
      c2s[idx] = w * (1.0f / 2048.0f) * TWD[(k * s1) & 63];
    }
  }
  if (t < 32) cs32[t] = make_float2(TWD[(2 * t) & 63], TWD[(2 * t + 48) & 63]);
  {
    float* tp = &T8[0][0][0];
#pragma unroll
    for (int q = 0; q < 34; ++q) tp[t + 256 * q] = 0.f;
  }
  __syncthreads();

  // ---- stage 1 ----
  {
    int wv = t >> 6;          // wave -> sorted-chunk of 64 modes
    int a  = t & 31;
    int ug = (t >> 5) & 1;    // half-wave -> unit group of 4
    float g[4] = {0.f, 0.f, 0.f, 0.f};
    int kprev = -1;
    for (int it = 0; it < 64; ++it) {
      int e = sorted[wv * 64 + it];
      int k = e >> 16, j = (e >> 8) & 255, l = e & 255;
      if (k != kprev) {                      // wave-uniform branch
        if (kprev >= 0) {
#pragma unroll
          for (int ui = 0; ui < 4; ++ui) {
            atomicAdd(&T8[ug * 4 + ui][a][kprev], g[ui]);
            g[ui] = 0.f;
          }
        }
        kprev = k;
      }
      float2 cs = cs32[(j * a) & 31];
#pragma unroll
      for (int ui = 0; ui < 4; ++ui) {
        float2 ov = om8[ug * 4 + ui][l];
        g[ui] = fmaf(ov.x, cs.x, g[ui]);
        g[ui] = fmaf(-ov.y, cs.y, g[ui]);
      }
    }
#pragma unroll
    for (int ui = 0; ui < 4; ++ui)
      atomicAdd(&T8[ug * 4 + ui][a][kprev], g[ui]);
  }
  __syncthreads();

  // ---- stage 2 ----
  int a  = t >> 3;
  int so = t & 7;
  float acc[8][8];
#pragma unroll
  for (int u = 0; u < 8; ++u)
#pragma unroll
    for (int s = 0; s < 8; ++s) acc[u][s] = 0.f;

  for (int k = 0; k < 33; ++k) {
    float4 cA = *(const float4*)&c2s[k * 64 + so * 8];
    float4 cB = *(const float4*)&c2s[k * 64 + so * 8 + 4];
#pragma unroll
    for (int u = 0; u < 8; ++u) {
      float tv = T8[u][a][k];
      acc[u][0] = fmaf(tv, cA.x, acc[u][0]);
      acc[u][1] = fmaf(tv, cA.y, acc[u][1]);
      acc[u][2] = fmaf(tv, cA.z, acc[u][2]);
      acc[u][3] = fmaf(tv, cA.w, acc[u][3]);
      acc[u][4] = fmaf(tv, cB.x, acc[u][4]);
      acc[u][5] = fmaf(tv, cB.y, acc[u][5]);
      acc[u][6] = fmaf(tv, cB.z, acc[u][6]);
      acc[u][7] = fmaf(tv, cB.w, acc[u][7]);
    }
  }
#pragma unroll
  for (int u = 0; u < 8; ++u) {
    float* yp = y + (ub + u) * 2048 + a * 64 + so * 8;
    *(float4*)(yp + 0) = make_float4(acc[u][0], acc[u][1], acc[u][2], acc[u][3]);
    *(float4*)(yp + 4) = make_float4(acc[u][4], acc[u][5], acc[u][6], acc[u][7]);
  }
}

extern "C" void kernel_launch(void* const* d_in, const int* in_sizes, int n_in,
                              void* d_out, int out_size, void* d_ws, size_t ws_size,
                              hipStream_t stream) {
  const float* x    = (const float*)d_in[0];
  const float* wre  = (const float*)d_in[1];
  const float* wim  = (const float*)d_in[2];
  const int*   mask = (const int*)d_in[3];

  float*  y  = (float*)d_out;
  float2* xm = (float2*)d_out;                        // scratch: dead before y written
  float2* omp = (float2*)d_ws;                        // 33.55 MB
  int* sorted = (int*)((char*)d_ws + 33554432);       // +1 KB

  k_sort<<<1, 256, 0, stream>>>(mask, sorted);
  k_fwd <<<4096, 256, 0, stream>>>(x, sorted, xm);
  k_mix <<<256, 512, 0, stream>>>(xm, wre, wim, omp);
  k_inv <<<2048, 256, 0, stream>>>(omp, sorted, y);
}

// Round 3
// 277.495 us; speedup vs baseline: 1.5413x; 1.1527x over previous
//
#include <hip/hip_runtime.h>

#define F1 33

// cos(2*pi*m/64); sin(2*pi*m/64) = TWD[(m+48)&63]
constexpr float TWD[64] = {
   1.00000000f,  0.99518473f,  0.98078528f,  0.95694034f,
   0.92387953f,  0.88192126f,  0.83146961f,  0.77301045f,
   0.70710678f,  0.63439328f,  0.55557023f,  0.47139674f,
   0.38268343f,  0.29028468f,  0.19509032f,  0.09801714f,
   0.00000000f, -0.09801714f, -0.19509032f, -0.29028468f,
  -0.38268343f, -0.47139674f, -0.55557023f, -0.63439328f,
  -0.70710678f, -0.77301045f, -0.83146961f, -0.88192126f,
  -0.92387953f, -0.95694034f, -0.98078528f, -0.99518473f,
  -1.00000000f, -0.99518473f, -0.98078528f, -0.95694034f,
  -0.92387953f, -0.88192126f, -0.83146961f, -0.77301045f,
  -0.70710678f, -0.63439328f, -0.55557023f, -0.47139674f,
  -0.38268343f, -0.29028468f, -0.19509032f, -0.09801714f,
   0.00000000f,  0.09801714f,  0.19509032f,  0.29028468f,
   0.38268343f,  0.47139674f,  0.55557023f,  0.63439328f,
   0.70710678f,  0.77301045f,  0.83146961f,  0.88192126f,
   0.92387953f,  0.95694034f,  0.98078528f,  0.99518473f,
};

// ---------------- K0: sort modes by k (tie: original l) + run table ---------
__global__ __launch_bounds__(256) void k_sort(const int* __restrict__ mask,
                                              int* __restrict__ sorted,
                                              int2* __restrict__ runs,
                                              int* __restrict__ n_runs) {
  __shared__ int ks[256];
  __shared__ int skey[256];
  int t = threadIdx.x;
  int mi = mask[t];
  int j = mi / F1;
  int k = mi - j * F1;
  ks[t] = k;
  __syncthreads();
  int mykey = (k << 8) | t;
  int rank = 0;
  for (int l2 = 0; l2 < 256; ++l2)
    rank += (((ks[l2] << 8) | l2) < mykey);
  sorted[rank] = (k << 16) | (j << 8) | t;
  skey[rank] = k;
  __syncthreads();
  // run boundaries over the k-sorted order
  int isb = (t == 0) || (skey[t] != skey[t - 1]);
  int rid = 0;                               // inclusive scan of boundary flags
  for (int l2 = 0; l2 <= t; ++l2)
    rid += ((l2 == 0) || (skey[l2] != skey[l2 - 1]));
  if (isb) runs[rid - 1] = make_int2(skey[t], t);
  if (t == 255) { runs[rid] = make_int2(0, 256); *n_runs = rid; }  // sentinel
}

// ---------------- K1 v2: forward ------------------------------------------
// 256 threads, 128 rows (4 units). Two threads per row (radix-2 DIT):
//  even lane: 17-bin DFT of even samples (E); odd lane: odd samples (O);
//  shfl_xor(1) exchange, butterfly combine X[k] = E[k] + w64^k O[k]
//  (k>16 via Hermitian conj). Stage B: one k-sorted mode per thread.
__global__ __launch_bounds__(256, 4) void k_fwd(const float* __restrict__ x,
                                                const int* __restrict__ sorted,
                                                float2* __restrict__ xm) {
  __shared__ float2 rbuf[128][35];   // [row][k], pad 35
  __shared__ float2 cs32[32];        // (cos,sin)(2*pi*m/32)
  int t = threadIdx.x;
  if (t < 32) cs32[t] = make_float2(TWD[(2 * t) & 63], TWD[(2 * t + 48) & 63]);

  int rl  = t >> 1;
  int par = t & 1;
  size_t row = (size_t)blockIdx.x * 128 + rl;
  const float4* xp = (const float4*)(x + row * 64);

  // my subsequence: even lane -> x[2m], odd lane -> x[2m+1]
  float f[32];
#pragma unroll
  for (int q = 0; q < 16; ++q) {
    float4 v = xp[q];
    f[2 * q + 0] = par ? v.y : v.x;
    f[2 * q + 1] = par ? v.w : v.z;
  }

  // 32-point DFT, bins 0..16 (rest via Hermitian symmetry)
  float mR[17], mI[17];
#pragma unroll
  for (int j = 0; j < 17; ++j) { mR[j] = 0.f; mI[j] = 0.f; }
#pragma unroll
  for (int m = 0; m < 32; ++m) {
    float xv = f[m];
#pragma unroll
    for (int j = 0; j < 17; ++j) {
      const int a = (2 * j * m) & 63;        // compile-time
      const float c = TWD[a];
      const float s = TWD[(a + 48) & 63];
      if (c != 0.0f) mR[j] = fmaf(xv,  c, mR[j]);
      if (s != 0.0f) mI[j] = fmaf(xv, -s, mI[j]);
    }
  }

  // exchange with partner lane (even<->odd)
  float oR[17], oI[17];
#pragma unroll
  for (int j = 0; j < 17; ++j) {
    oR[j] = __shfl_xor(mR[j], 1, 64);
    oI[j] = __shfl_xor(mI[j], 1, 64);
  }

  if (par == 0) {
#pragma unroll
    for (int k = 0; k <= 16; ++k) {
      const float wr = TWD[k];
      const float s  = TWD[(k + 48) & 63];
      float XR = mR[k];
      float XI = mI[k];
      if (s  != 0.0f) { XR = fmaf( s, oI[k], XR); XI = fmaf(-s, oR[k], XI); }
      if (wr != 0.0f) { XR = fmaf(wr, oR[k], XR); XI = fmaf(wr, oI[k], XI); }
      rbuf[rl][k] = make_float2(XR, XI);
    }
  } else {
#pragma unroll
    for (int k = 17; k <= 31; ++k) {
      const float wr = TWD[k];
      const float s  = TWD[(k + 48) & 63];
      const int p = 32 - k;
      float XR = oR[p];
      float XI = -oI[p];
      if (s  != 0.0f) { XR = fmaf(-s, mI[p], XR); XI = fmaf(-s, mR[p], XI); }
      if (wr != 0.0f) { XR = fmaf(wr, mR[p], XR); XI = fmaf(-wr, mI[p], XI); }
      rbuf[rl][k] = make_float2(XR, XI);
    }
    rbuf[rl][32] = make_float2(oR[0] - mR[0], 0.0f);
  }
  __syncthreads();

  // ---- stage B: thread t owns sorted mode t, accumulates 4 units ----
  int e = sorted[t];
  int k = e >> 16, j = (e >> 8) & 255, l = e & 255;
  float2 acc[4];
#pragma unroll
  for (int u = 0; u < 4; ++u) acc[u] = make_float2(0.f, 0.f);

#pragma unroll 4
  for (int s0 = 0; s0 < 32; ++s0) {
    float2 cs = cs32[(j * s0) & 31];         // (cos, sin)
#pragma unroll
    for (int u = 0; u < 4; ++u) {
      float2 rv = rbuf[u * 32 + s0][k];      // wave: few distinct k -> broadcast
      acc[u].x = fmaf(rv.x, cs.x, fmaf(rv.y,  cs.y, acc[u].x));
      acc[u].y = fmaf(rv.y, cs.x, fmaf(-rv.x, cs.y, acc[u].y));
    }
  }
  size_t ub = (size_t)blockIdx.x * 4;
#pragma unroll
  for (int u = 0; u < 4; ++u)
    xm[(ub + u) * 256 + l] = acc[u];
}

// ---------------- K2: om[b,h,o,l] = sum_i xm[b,h,i,l] * W[h,i,o,l] ----------
__global__ __launch_bounds__(512) void k_mix(const float2* __restrict__ xm,
                                             const float* __restrict__ wr,
                                             const float* __restrict__ wi,
                                             float2* __restrict__ om) {
  __shared__ float2 Asm[8][33][9];   // [i][b][l] (b-dim 33, l-dim 9 pads)
  __shared__ float2 Wsm[8][8][64];   // [i][l][o]
  int t = threadIdx.x;
  int h  = blockIdx.x >> 5;
  int lb = (blockIdx.x & 31) * 8;

  int o  = t & 63;
  int lp = (t >> 6) & 3;
  int bh = t >> 8;                   // 0/1 -> b range 16

  float2 acc[16][2];
#pragma unroll
  for (int bb = 0; bb < 16; ++bb) {
    acc[bb][0] = make_float2(0.f, 0.f);
    acc[bb][1] = make_float2(0.f, 0.f);
  }

  for (int ic = 0; ic < 8; ++ic) {
    __syncthreads();
#pragma unroll
    for (int q = 0; q < 2; ++q) {
      int c = t + 512 * q;
      int lp4 = c & 3, ii = (c >> 2) & 7, b = c >> 5;
      const float4* src = (const float4*)(xm + (size_t)(((b * 8 + h) * 64) + ic * 8 + ii) * 256 + lb + lp4 * 2);
      float4 v = *src;
      Asm[ii][b][lp4 * 2 + 0] = make_float2(v.x, v.y);
      Asm[ii][b][lp4 * 2 + 1] = make_float2(v.z, v.w);
    }
#pragma unroll
    for (int q = 0; q < 2; ++q) {
      int c = t + 512 * q;
      int lh = c & 1, oo = (c >> 1) & 63, ii = c >> 7;
      size_t gidx = (size_t)((h * 64 + ic * 8 + ii) * 64 + oo) * 256 + lb + lh * 4;
      float4 vr = *(const float4*)(wr + gidx);
      float4 vi = *(const float4*)(wi + gidx);
      Wsm[ii][lh * 4 + 0][oo] = make_float2(vr.x, vi.x);
      Wsm[ii][lh * 4 + 1][oo] = make_float2(vr.y, vi.y);
      Wsm[ii][lh * 4 + 2][oo] = make_float2(vr.z, vi.z);
      Wsm[ii][lh * 4 + 3][oo] = make_float2(vr.w, vi.w);
    }
    __syncthreads();
#pragma unroll
    for (int i = 0; i < 8; ++i) {
      float2 w0 = Wsm[i][lp * 2 + 0][o];
      float2 w1 = Wsm[i][lp * 2 + 1][o];
#pragma unroll
      for (int bb = 0; bb < 16; ++bb) {
        int b = bh * 16 + bb;
        float2 a0 = Asm[i][b][lp * 2 + 0];
        float2 a1 = Asm[i][b][lp * 2 + 1];
        acc[bb][0].x = fmaf(a0.x, w0.x, fmaf(-a0.y, w0.y, acc[bb][0].x));
        acc[bb][0].y = fmaf(a0.x, w0.y, fmaf( a0.y, w0.x, acc[bb][0].y));
        acc[bb][1].x = fmaf(a1.x, w1.x, fmaf(-a1.y, w1.y, acc[bb][1].x));
        acc[bb][1].y = fmaf(a1.x, w1.y, fmaf( a1.y, w1.x, acc[bb][1].y));
      }
    }
  }
#pragma unroll
  for (int bb = 0; bb < 16; ++bb) {
    int b = bh * 16 + bb;
    float4 v = make_float4(acc[bb][0].x, acc[bb][0].y, acc[bb][1].x, acc[bb][1].y);
    *(float4*)(om + (size_t)(((b * 8 + h) * 64) + o) * 256 + lb + lp * 2) = v;
  }
}

// ---------------- K3 v3: inverse, fused (no T buffer, no atomics) -----------
// 8 units/block, 256 threads: thread = (u, a) owns y[unit][a][0..63] in regs.
// Two-level loop over k-runs: accumulate g = sum Re(om*e^{ija}) over the run,
// then spread g into 64 accumulators via broadcast c2s row (static indexing).
__global__ __launch_bounds__(256, 4) void k_inv(const float2* __restrict__ om,
                                                const int* __restrict__ sorted,
                                                const int2* __restrict__ runs,
                                                const int* __restrict__ n_runs_p,
                                                float* __restrict__ y) {
  __shared__ float2 om8[8][256];     // 16.4 KB
  __shared__ float4 c2s4[33 * 16];   // 8.45 KB: c2s[k][s1] as float4 rows
  __shared__ float2 cs32[32];
  __shared__ int    smodes[256];
  int t = threadIdx.x;
  size_t ub = (size_t)blockIdx.x * 8;

  {
    const float4* omv = (const float4*)(om + ub * 256);
    float4* dst = (float4*)&om8[0][0];
#pragma unroll
    for (int q = 0; q < 4; ++q) dst[t + 256 * q] = omv[t + 256 * q];
  }
#pragma unroll
  for (int q = 0; q < 3; ++q) {
    int idx = t + 256 * q;
    if (idx < 528) {
      int k = idx >> 4, s4 = idx & 15;
      float w = (k == 0 || k == 32) ? (1.0f / 2048.0f) : (2.0f / 2048.0f);
      float4 v;
      v.x = w * TWD[(k * (s4 * 4 + 0)) & 63];
      v.y = w * TWD[(k * (s4 * 4 + 1)) & 63];
      v.z = w * TWD[(k * (s4 * 4 + 2)) & 63];
      v.w = w * TWD[(k * (s4 * 4 + 3)) & 63];
      c2s4[idx] = v;
    }
  }
  if (t < 32) cs32[t] = make_float2(TWD[(2 * t) & 63], TWD[(2 * t + 48) & 63]);
  smodes[t] = sorted[t];
  __syncthreads();

  int u = t >> 5;
  int a = t & 31;
  int nr = *n_runs_p;                       // uniform scalar

  float4 acc[16];
#pragma unroll
  for (int q = 0; q < 16; ++q) acc[q] = make_float4(0.f, 0.f, 0.f, 0.f);

  int2 rcur = runs[0];
  for (int r = 0; r < nr; ++r) {
    int2 rnext = runs[r + 1];
    int k = rcur.x;
    float g = 0.f;
    for (int it = rcur.y; it < rnext.y; ++it) {
      int e = smodes[it];                    // broadcast
      int j = (e >> 8) & 255, l = e & 255;
      float2 ov = om8[u][l];                 // 2 addrs / wave
      float2 cs = cs32[(j * a) & 31];
      g = fmaf(ov.x, cs.x, g);
      g = fmaf(-ov.y, cs.y, g);
    }
    const float4* crow = &c2s4[k * 16];      // broadcast row
#pragma unroll
    for (int q = 0; q < 16; ++q) {
      float4 c = crow[q];
      acc[q].x = fmaf(g, c.x, acc[q].x);
      acc[q].y = fmaf(g, c.y, acc[q].y);
      acc[q].z = fmaf(g, c.z, acc[q].z);
      acc[q].w = fmaf(g, c.w, acc[q].w);
    }
    rcur = rnext;
  }

  float4* yp = (float4*)(y + (ub + u) * 2048 + a * 64);
#pragma unroll
  for (int q = 0; q < 16; ++q) yp[q] = acc[q];
}

extern "C" void kernel_launch(void* const* d_in, const int* in_sizes, int n_in,
                              void* d_out, int out_size, void* d_ws, size_t ws_size,
                              hipStream_t stream) {
  const float* x    = (const float*)d_in[0];
  const float* wre  = (const float*)d_in[1];
  const float* wim  = (const float*)d_in[2];
  const int*   mask = (const int*)d_in[3];

  float*  y  = (float*)d_out;
  float2* xm = (float2*)d_out;                        // scratch: dead before y written
  float2* omp = (float2*)d_ws;                        // 33.55 MB
  char* base = (char*)d_ws;
  int*  sorted = (int*)(base + 33554432);             // 1 KB
  int2* runs   = (int2*)(base + 33555456);            // 34 * 8 B
  int*  n_runs = (int*)(base + 33555968);             // 4 B

  k_sort<<<1, 256, 0, stream>>>(mask, sorted, runs, n_runs);
  k_fwd <<<4096, 256, 0, stream>>>(x, sorted, xm);
  k_mix <<<256, 512, 0, stream>>>(xm, wre, wim, omp);
  k_inv <<<2048, 256, 0, stream>>>(omp, sorted, runs, n_runs, y);
}